// Round 3
// baseline (587.610 us; speedup 1.0000x reference)
//
#include <hip/hip_runtime.h>

// LIF charge->fire->hard-reset scan over T=4 timesteps. Identical kernel to R2.
// MEASUREMENT ROUND: kernel launched TWICE (idempotent, same output) so that
// dur_us_new - dur_us_R2 = one kernel's true duration, disambiguating harness
// fixed overhead (restore+poison fills) from kernel time, since rocprof top-5
// only shows the 195us poison fills and hides our dispatch.

typedef float f4 __attribute__((ext_vector_type(4)));

constexpr int T_STEPS = 4;

__global__ __launch_bounds__(256) void lif_kernel(const f4* __restrict__ x,
                                                  f4* __restrict__ out,
                                                  long long n4, long long half) {
    long long i = (long long)blockIdx.x * blockDim.x + threadIdx.x;
    if (i >= half) return;
    long long j = i + half;

    f4 v0 = {0.f, 0.f, 0.f, 0.f};
    f4 v1 = {0.f, 0.f, 0.f, 0.f};

#pragma unroll
    for (int t = 0; t < T_STEPS; ++t) {
        f4 x0 = __builtin_nontemporal_load(x + (long long)t * n4 + i);
        f4 x1 = __builtin_nontemporal_load(x + (long long)t * n4 + j);
        f4 s0, s1;

#pragma unroll
        for (int k = 0; k < 4; ++k) {
            // exact reference op order: v_charged = v + (x - v) / 2
            v0[k] = v0[k] + (x0[k] - v0[k]) * 0.5f;
            float sp0 = (v0[k] >= 1.0f) ? 1.0f : 0.0f;
            s0[k] = sp0;
            v0[k] = (sp0 != 0.0f) ? 0.0f : v0[k];

            v1[k] = v1[k] + (x1[k] - v1[k]) * 0.5f;
            float sp1 = (v1[k] >= 1.0f) ? 1.0f : 0.0f;
            s1[k] = sp1;
            v1[k] = (sp1 != 0.0f) ? 0.0f : v1[k];
        }

        __builtin_nontemporal_store(s0, out + (long long)t * n4 + i);
        __builtin_nontemporal_store(s1, out + (long long)t * n4 + j);
    }
}

extern "C" void kernel_launch(void* const* d_in, const int* in_sizes, int n_in,
                              void* d_out, int out_size, void* d_ws, size_t ws_size,
                              hipStream_t stream) {
    const float* x = (const float*)d_in[0];
    float* out = (float*)d_out;

    long long total = (long long)in_sizes[0];   // T * N
    long long n = total / T_STEPS;              // neurons per timestep (19,365,888)
    long long n4 = n / 4;                       // float4 groups per timestep (4,841,472)
    long long half = n4 / 2;                    // 2,420,736 (divides evenly)

    int block = 256;
    long long grid = (half + block - 1) / block;  // 9456 blocks

    // Launch twice: second launch recomputes identical output (pure function).
    // dur_us - 480 (R2 single-launch) = one kernel's duration.
    lif_kernel<<<(int)grid, block, 0, stream>>>((const f4*)x, (f4*)out, n4, half);
    lif_kernel<<<(int)grid, block, 0, stream>>>((const f4*)x, (f4*)out, n4, half);
}

// Round 4
// 483.652 us; speedup vs baseline: 1.2149x; 1.2149x over previous
//
#include <hip/hip_runtime.h>

// LIF charge->fire->hard-reset scan over T=4 timesteps.
// x_seq: [T, N] fp32 (T outermost), out: [T, N] fp32 spikes in {0,1}.
// v0 = 0; v_charged = v + (x - v)*0.5f; spike = (v_charged >= 1); v = spike ? 0 : v_charged.
//
// Pure streaming kernel, 620 MB compulsory traffic. Measured (R3 double-launch
// differential): single dispatch = 107.5 us = 5.77 TB/s = 92% of the 6.29 TB/s
// float4-copy ceiling. Total bench dur_us carries ~373 us of fixed harness
// restore/poison overhead on the same stream.
//
// Each thread owns FOUR float4 groups at stride n4/4 -> 16 nontemporal
// dwordx4 loads in flight (MLP), coalesced 16B/lane, v carried in registers
// across the T loop. nt loads/stores skip L2/L3 allocation (read-once /
// write-once data).

typedef float f4 __attribute__((ext_vector_type(4)));

constexpr int T_STEPS = 4;
constexpr int G = 4;  // float4 groups per thread

__global__ __launch_bounds__(256) void lif_kernel(const f4* __restrict__ x,
                                                  f4* __restrict__ out,
                                                  long long n4, long long q) {
    long long i = (long long)blockIdx.x * blockDim.x + threadIdx.x;
    if (i >= q) return;

    f4 v[G];
#pragma unroll
    for (int g = 0; g < G; ++g) v[g] = (f4){0.f, 0.f, 0.f, 0.f};

#pragma unroll
    for (int t = 0; t < T_STEPS; ++t) {
        const f4* xt = x + (long long)t * n4;
        f4* ot = out + (long long)t * n4;

        f4 xv[G];
#pragma unroll
        for (int g = 0; g < G; ++g)
            xv[g] = __builtin_nontemporal_load(xt + i + (long long)g * q);

        f4 s[G];
#pragma unroll
        for (int g = 0; g < G; ++g) {
#pragma unroll
            for (int k = 0; k < 4; ++k) {
                // exact reference op order: v_charged = v + (x - v) / 2
                v[g][k] = v[g][k] + (xv[g][k] - v[g][k]) * 0.5f;
                float sp = (v[g][k] >= 1.0f) ? 1.0f : 0.0f;
                s[g][k] = sp;
                v[g][k] = (sp != 0.0f) ? 0.0f : v[g][k];
            }
        }

#pragma unroll
        for (int g = 0; g < G; ++g)
            __builtin_nontemporal_store(s[g], ot + i + (long long)g * q);
    }
}

extern "C" void kernel_launch(void* const* d_in, const int* in_sizes, int n_in,
                              void* d_out, int out_size, void* d_ws, size_t ws_size,
                              hipStream_t stream) {
    const float* x = (const float*)d_in[0];
    float* out = (float*)d_out;

    long long total = (long long)in_sizes[0];   // T * N
    long long n = total / T_STEPS;              // neurons per timestep (19,365,888)
    long long n4 = n / 4;                       // float4 groups per timestep (4,841,472)
    long long q = n4 / G;                       // 1,210,368 (divides evenly)

    int block = 256;
    long long grid = (q + block - 1) / block;   // 4728 blocks

    lif_kernel<<<(int)grid, block, 0, stream>>>((const f4*)x, (f4*)out, n4, q);
}